// Round 12
// baseline (265.795 us; speedup 1.0000x reference)
//
#include <hip/hip_runtime.h>
#include <hip/hip_fp16.h>
#include <math.h>

constexpr int N_NODES = 100000;
constexpr int N_EDGES = 3200000;
constexpr int IN_F = 512;
constexpr int HID = 64;
constexpr int NCLS = 32;
constexpr int CAP = 80;            // per-node slot capacity (multiple of 16); P(indeg>=80) ~ 1e-13
constexpr int SHIFT = 9;           // 512 nodes per coarse bucket
constexpr int NB = 196;            // ceil(100000/512)
constexpr int BCAPC = 16976;       // per-bucket capacity: mean 16327 + ~5 sigma
constexpr int CHUNK = 8192;        // edges per partition block (big: fewer gtail atomics/line)
constexpr int SENT = N_NODES;      // sentinel node id (zeroed rows)

constexpr int GEMM1_BLOCKS = (N_NODES + 63) / 64;            // 1563
constexpr int PART_BLOCKS  = (N_EDGES + CHUNK - 1) / CHUNK;  // 391

typedef short short8 __attribute__((ext_vector_type(8)));    // 8 bf16 in 4 VGPRs
typedef float f32x4 __attribute__((ext_vector_type(4)));
typedef int intx4 __attribute__((ext_vector_type(4)));

// ---------- bf16 helpers (bit-level, RNE) ----------
__device__ __forceinline__ unsigned short f2bf(float f) {
    union { float f; unsigned int u; } v; v.f = f;
    unsigned int r = (v.u + 0x7fffu + ((v.u >> 16) & 1u)) >> 16;
    return (unsigned short)r;
}
__device__ __forceinline__ float bf2f(unsigned short h) {
    union { unsigned int u; float f; } v; v.u = ((unsigned int)h) << 16;
    return v.f;
}
// ---------- fp8 e5m2 helpers (top byte of f16, RNE) ----------
__device__ __forceinline__ unsigned char f2e5(float f) {
    unsigned short u = __half_as_ushort(__float2half(f));
    return (unsigned char)((u + 0x7Fu + ((u >> 8) & 1u)) >> 8);
}
__device__ __forceinline__ float e52f(unsigned char b) {
    return __half2float(__ushort_as_half((unsigned short)((unsigned short)b << 8)));
}
// ---------- async 16B global->LDS ----------
__device__ __forceinline__ void gload16(const void* g, void* l) {
    __builtin_amdgcn_global_load_lds((const __attribute__((address_space(1))) unsigned int*)g,
                                     (__attribute__((address_space(3))) unsigned int*)l,
                                     16, 0, 0);
}

// ---------------- prep: W1T bf16 [64][512]; zero sentinel rows + gtail + cnt ----------------
__global__ __launch_bounds__(256) void k_prep(const float* __restrict__ W1,
                                              unsigned short* __restrict__ W1T,
                                              unsigned char* __restrict__ h1s,
                                              unsigned char* __restrict__ h2s,
                                              int* __restrict__ gtail,
                                              int* __restrict__ cnt) {
    // all blocks: zero cnt stripe (rank counters for k_phase2's global atomics)
    for (int i = blockIdx.x * 256 + threadIdx.x; i < N_NODES; i += 129 * 256)
        cnt[i] = 0;
    if (blockIdx.x == 128) {
        int t = threadIdx.x;
        if (t < HID)  h1s[(size_t)SENT * HID + t] = 0;
        if (t < NCLS) h2s[(size_t)SENT * NCLS + t] = 0;
        for (int i = t; i < NB * 16; i += 256) gtail[i] = 0;   // replaces hipMemsetAsync
        return;
    }
    int t = blockIdx.x * 256 + threadIdx.x;     // 0..32767
    int k = t >> 6, c = t & 63;
    W1T[(size_t)c * IN_F + k] = f2bf(W1[(size_t)k * HID + c]);
}

// ---------------- partition: 8192 edges/block, 512 thr, 1-pass rank + shfl scan ----------------

__global__ __launch_bounds__(512) void k_part(const int* __restrict__ src,
                                              const int* __restrict__ dst,
                                              int* __restrict__ gtail,   // [NB*16] line-padded
                                              int* __restrict__ recs) {  // [NB*BCAPC] packed ln<<17|src
    __shared__ alignas(16) char smem[47168];
    int* buf            = (int*)smem;                    // 32768 B
    unsigned char* bbuf = (unsigned char*)(smem + 32768);// 8192 B
    int* loc   = (int*)(smem + 40960);                   // 513 ints
    int* lh    = (int*)(smem + 43012);                   // 512 ints
    int* lbase = (int*)(smem + 45060);                   // 512 ints
    int* wsum  = (int*)(smem + 47108);                   // 8 ints
    const int tid = threadIdx.x;
    const int lane = tid & 63;
    const int wv = tid >> 6;                             // 0..7
    const int c0 = blockIdx.x * CHUNK;
    const int cnum = min(CHUNK, N_EDGES - c0);
    lh[tid] = 0;
    __syncthreads();
    int dd[16], ss[16], rk[16];
    #pragma unroll
    for (int k = 0; k < 16; ++k) {
        int i = k * 512 + tid;
        if (i < cnum) {
            dd[k] = dst[c0 + i];
            ss[k] = src[c0 + i];
            rk[k] = atomicAdd(&lh[dd[k] >> SHIFT], 1);   // count AND local rank (LDS)
        }
    }
    __syncthreads();
    int orig = lh[tid];
    // barrier-free scan: wave shfl inclusive scan + wave-sum combine
    int v = orig;
    #pragma unroll
    for (int off = 1; off < 64; off <<= 1) {
        int t = __shfl_up(v, off, 64);
        if (lane >= off) v += t;
    }
    if (lane == 63) wsum[wv] = v;
    __syncthreads();
    int pre = 0;
    #pragma unroll
    for (int k = 0; k < 8; ++k) if (k < wv) pre += wsum[k];
    int incl = v + pre;
    loc[tid] = incl - orig;                              // exclusive prefix
    if (tid < NB && orig > 0) lbase[tid] = atomicAdd(&gtail[tid * 16], orig);
    __syncthreads();
    #pragma unroll
    for (int k = 0; k < 16; ++k) {
        int i = k * 512 + tid;
        if (i < cnum) {
            int b = dd[k] >> SHIFT;
            int pos = loc[b] + rk[k];
            buf[pos] = ((dd[k] & 511) << 17) | ss[k];
            bbuf[pos] = (unsigned char)b;
        }
    }
    __syncthreads();
    for (int i = tid; i < cnum; i += 512) {              // contiguous run write-out
        int b = bbuf[i];
        int idx = lbase[b] + (i - loc[b]);
        if (idx < BCAPC) recs[(size_t)b * BCAPC + idx] = buf[i];
    }
}

// ---------------- phase 2a (784 blocks, 512 thr): slot placement, global-atomic ranks ----
// 4 blocks per bucket, each placing a quarter of the recs; rank comes from a
// device-scope atomicAdd on cnt[node] (old LDS scnt limited this to 196 blocks
// = 0.77 blocks/CU, leaving the machine idle and latency exposed).

__global__ __launch_bounds__(512) void k_phase2(const int* __restrict__ gtail,
                                                const int* __restrict__ recs,
                                                int* __restrict__ slots,
                                                int* __restrict__ cnt) {
    const int b = blockIdx.x >> 2;                       // bucket
    const int q = blockIdx.x & 3;                        // quarter
    int nrec = min(gtail[b * 16], BCAPC);
    int n4 = (nrec + 3) >> 2;
    int lo = q * n4;
    int hi = min(nrec, lo + n4);
    const int* rb = recs + (size_t)b * BCAPC;
    for (int i = lo + threadIdx.x; i < hi; i += 512) {
        int r = rb[i];
        int ln = r >> 17;
        int s  = r & 0x1FFFF;
        int node = (b << SHIFT) + ln;
        int p = atomicAdd(&cnt[node], 1);                // global rank
        if (p < CAP) slots[(size_t)node * CAP + p] = s;
    }
}

// ---------------- phase 2b: sentinel pad (to 16) + dinv (needs final cnt) ----------------

__global__ __launch_bounds__(512) void k_phase2b(int* __restrict__ slots,
                                                 const int* __restrict__ cnt,
                                                 float* __restrict__ dinv) {
    int node = blockIdx.x * 512 + threadIdx.x;
    if (node >= N_NODES) return;
    int c = cnt[node];
    dinv[node] = rsqrtf(1.0f + (float)c);
    int c2 = min(c, CAP);
    int degp = (c2 + 15) & ~15;                          // pad to 16 for unroll-16 gathers
    for (int p = c2; p < degp; ++p) slots[(size_t)node * CAP + p] = SENT;
}

// ---------------- GEMM1: h1s = fp8(dinv * (x @ W1)), 64x64 tile, 4-deep async pipeline ----

__global__ __launch_bounds__(256) void k_gemm1(const float* __restrict__ x,
                                               const unsigned short* __restrict__ W1T,
                                               const float* __restrict__ dinv,
                                               unsigned char* __restrict__ h1s) {
    __shared__ alignas(16) char smem[49152];
    float* Xf = (float*)smem;                            // [4][64][32] f32, 32768 B
    unsigned short* Wf = (unsigned short*)(smem + 32768);// [4][64][32] bf16, 16384 B
    const int tid = threadIdx.x;
    const int lane = tid & 63;
    const int row0 = blockIdx.x * 64;
    const int w = tid >> 6;
    const int r0l = (w >> 1) * 32;
    const int c0l = (w & 1) * 32;
    const int lrow = lane & 15;
    const int lkb = (lane >> 4) << 3;                    // k offset 0,8,16,24
    f32x4 acc00 = {0.f, 0.f, 0.f, 0.f}, acc01 = acc00, acc10 = acc00, acc11 = acc00;

    const int rowA0 = tid >> 3;            // issue0: rows 0..31
    const int rowA1 = 32 + (tid >> 3);     // issue1: rows 32..63
    const int gA = tid & 7;                // 16B granule within 128B row
    const float* srcX0 = x + (size_t)min(row0 + rowA0, N_NODES - 1) * IN_F + ((gA ^ (rowA0 & 7)) << 2);
    const float* srcX1 = x + (size_t)min(row0 + rowA1, N_NODES - 1) * IN_F + ((gA ^ (rowA1 & 7)) << 2);
    const int rowW = tid >> 2;
    const int gW = tid & 3;                // 16B granule within 64B row
    const unsigned short* srcW = W1T + (size_t)rowW * IN_F + ((gW ^ (rowW & 3)) << 3);
    char* ldsX0 = smem + (w << 10);
    char* ldsX1 = smem + 4096 + (w << 10);
    char* ldsW  = smem + 32768 + (w << 10);

    #pragma unroll
    for (int s = 0; s < 3; ++s) {
        gload16(srcX0 + s * 32, ldsX0 + s * 8192);
        gload16(srcX1 + s * 32, ldsX1 + s * 8192);
        gload16(srcW  + s * 32, ldsW  + s * 4096);
    }

    const int RA = r0l + lrow, RA2 = RA + 16;
    const int RB = c0l + lrow, RB2 = RB + 16;
    const int qx = lkb >> 2;               // X granule pair base (0,2,4,6)
    const int qw = lkb >> 3;               // W granule (0..3)
    const int sxA  = ((qx ^ (RA & 7)) << 2),  sxA_ = (((qx + 1) ^ (RA & 7)) << 2);
    const int sxB  = ((qx ^ (RA2 & 7)) << 2), sxB_ = (((qx + 1) ^ (RA2 & 7)) << 2);
    const int swB  = ((qw ^ (RB & 3)) << 3);
    const int swB2 = ((qw ^ (RB2 & 3)) << 3);

#define GEMM_COMPUTE(S)                                                          \
    {                                                                            \
        const int b_ = (S) & 3;                                                  \
        const float* xrA = Xf + b_ * 2048 + RA * 32;                             \
        const float* xrB = Xf + b_ * 2048 + RA2 * 32;                            \
        f32x4 va0 = *(const f32x4*)(xrA + sxA);                                  \
        f32x4 va1 = *(const f32x4*)(xrA + sxA_);                                 \
        f32x4 vb0 = *(const f32x4*)(xrB + sxB);                                  \
        f32x4 vb1 = *(const f32x4*)(xrB + sxB_);                                 \
        const unsigned short* wr = Wf + b_ * 2048;                               \
        short8 b0 = *(const short8*)(wr + RB * 32 + swB);                        \
        short8 b1 = *(const short8*)(wr + RB2 * 32 + swB2);                      \
        short8 a0, a1;                                                           \
        a0[0] = (short)f2bf(va0[0]); a0[1] = (short)f2bf(va0[1]);                \
        a0[2] = (short)f2bf(va0[2]); a0[3] = (short)f2bf(va0[3]);                \
        a0[4] = (short)f2bf(va1[0]); a0[5] = (short)f2bf(va1[1]);                \
        a0[6] = (short)f2bf(va1[2]); a0[7] = (short)f2bf(va1[3]);                \
        a1[0] = (short)f2bf(vb0[0]); a1[1] = (short)f2bf(vb0[1]);                \
        a1[2] = (short)f2bf(vb0[2]); a1[3] = (short)f2bf(vb0[3]);                \
        a1[4] = (short)f2bf(vb1[0]); a1[5] = (short)f2bf(vb1[1]);                \
        a1[6] = (short)f2bf(vb1[2]); a1[7] = (short)f2bf(vb1[3]);                \
        acc00 = __builtin_amdgcn_mfma_f32_16x16x32_bf16(a0, b0, acc00, 0, 0, 0); \
        acc01 = __builtin_amdgcn_mfma_f32_16x16x32_bf16(a0, b1, acc01, 0, 0, 0); \
        acc10 = __builtin_amdgcn_mfma_f32_16x16x32_bf16(a1, b0, acc10, 0, 0, 0); \
        acc11 = __builtin_amdgcn_mfma_f32_16x16x32_bf16(a1, b1, acc11, 0, 0, 0); \
    }

    for (int s = 0; s < 14; ++s) {
        asm volatile("s_waitcnt vmcnt(6)" ::: "memory");   // step-s loads landed (mine)
        __builtin_amdgcn_s_barrier();                      // ...and everyone's
        __builtin_amdgcn_sched_barrier(0);
        if (s < 13) {
            gload16(srcX0 + (s + 3) * 32, ldsX0 + ((s + 3) & 3) * 8192);
            gload16(srcX1 + (s + 3) * 32, ldsX1 + ((s + 3) & 3) * 8192);
            gload16(srcW  + (s + 3) * 32, ldsW  + ((s + 3) & 3) * 4096);
        }
        GEMM_COMPUTE(s);
    }
    asm volatile("s_waitcnt vmcnt(3)" ::: "memory");
    __builtin_amdgcn_s_barrier();
    __builtin_amdgcn_sched_barrier(0);
    GEMM_COMPUTE(14);
    asm volatile("s_waitcnt vmcnt(0)" ::: "memory");
    __builtin_amdgcn_s_barrier();
    __builtin_amdgcn_sched_barrier(0);
    GEMM_COMPUTE(15);
#undef GEMM_COMPUTE

    const int vr0 = row0 + r0l + ((lane >> 4) << 2);
    const int gc0 = c0l + (lane & 15);
    #pragma unroll
    for (int v = 0; v < 4; ++v) {
        int gr = vr0 + v;
        if (gr < N_NODES) {
            float dv = dinv[gr];
            h1s[(size_t)gr * HID + gc0]      = f2e5(acc00[v] * dv);
            h1s[(size_t)gr * HID + gc0 + 16] = f2e5(acc01[v] * dv);
        }
        int gr2 = gr + 16;
        if (gr2 < N_NODES) {
            float dv2 = dinv[gr2];
            h1s[(size_t)gr2 * HID + gc0]      = f2e5(acc10[v] * dv2);
            h1s[(size_t)gr2 * HID + gc0 + 16] = f2e5(acc11[v] * dv2);
        }
    }
}

// ---------------- fused gather1 + GEMM2: h2s = fp8(dinv * (relu(agg) @ W2)) ----------------
// Wave-per-node, grid-stride; 16 gathers in flight per round. Slot loads are
// TEMPORAL (retained in L2) so k_out's second pass over slots hits cache.

__global__ __launch_bounds__(256) void k_gather1(const int* __restrict__ cnt,
                                                 const int* __restrict__ slots,
                                                 const float* __restrict__ dinv,
                                                 const unsigned char* __restrict__ h1s,
                                                 const float* __restrict__ b1,
                                                 const float* __restrict__ W2,
                                                 unsigned char* __restrict__ h2s) {
    __shared__ alignas(16) float hsh[4][64];
    const int lane = threadIdx.x & 63;
    const int wv = threadIdx.x >> 6;
    const int cls = lane & 31;
    const int half = lane >> 5;
    float w[32];
    #pragma unroll
    for (int j = 0; j < 32; ++j)
        w[j] = W2[(size_t)(half * 32 + j) * NCLS + cls];
    const float bb = b1[lane];
    const int nw = gridDim.x * 4;
    for (int n0 = blockIdx.x * 4 + wv; n0 < N_NODES; n0 += nw) {
        const int n = __builtin_amdgcn_readfirstlane(n0);
        float dn = dinv[n];
        int deg = min(cnt[n], CAP);
        int degp = (deg + 15) & ~15;
        size_t base = (size_t)n * CAP;
        float a0 = e52f(h1s[(((unsigned)n) << 6) + lane]);   // self (already dinv[n]-scaled)
        float a1 = 0.f, a2 = 0.f, a3 = 0.f, a4 = 0.f, a5 = 0.f, a6 = 0.f, a7 = 0.f;
        for (int j = 0; j < degp; j += 16) {
            intx4 sa = *reinterpret_cast<const intx4*>(&slots[base + j]);
            intx4 sb = *reinterpret_cast<const intx4*>(&slots[base + j + 4]);
            intx4 sc = *reinterpret_cast<const intx4*>(&slots[base + j + 8]);
            intx4 sd = *reinterpret_cast<const intx4*>(&slots[base + j + 12]);
            a0 += e52f(h1s[(((unsigned)sa.x) << 6) + lane]);
            a1 += e52f(h1s[(((unsigned)sa.y) << 6) + lane]);
            a2 += e52f(h1s[(((unsigned)sa.z) << 6) + lane]);
            a3 += e52f(h1s[(((unsigned)sa.w) << 6) + lane]);
            a4 += e52f(h1s[(((unsigned)sb.x) << 6) + lane]);
            a5 += e52f(h1s[(((unsigned)sb.y) << 6) + lane]);
            a6 += e52f(h1s[(((unsigned)sb.z) << 6) + lane]);
            a7 += e52f(h1s[(((unsigned)sb.w) << 6) + lane]);
            a0 += e52f(h1s[(((unsigned)sc.x) << 6) + lane]);
            a1 += e52f(h1s[(((unsigned)sc.y) << 6) + lane]);
            a2 += e52f(h1s[(((unsigned)sc.z) << 6) + lane]);
            a3 += e52f(h1s[(((unsigned)sc.w) << 6) + lane]);
            a4 += e52f(h1s[(((unsigned)sd.x) << 6) + lane]);
            a5 += e52f(h1s[(((unsigned)sd.y) << 6) + lane]);
            a6 += e52f(h1s[(((unsigned)sd.z) << 6) + lane]);
            a7 += e52f(h1s[(((unsigned)sd.w) << 6) + lane]);
        }
        float v = fmaf(((a0 + a1) + (a2 + a3)) + ((a4 + a5) + (a6 + a7)), dn, bb);
        v = fmaxf(v, 0.f);                     // h1r value for feature `lane`, fp32
        hsh[wv][lane] = v;
        // in-wave 64x32 matvec: lane (cls,half) accumulates its half of k
        float acc = 0.f;
        #pragma unroll
        for (int q = 0; q < 8; ++q) {
            f32x4 hv = *reinterpret_cast<const f32x4*>(&hsh[wv][half * 32 + q * 4]);
            acc = fmaf(hv.x, w[q * 4 + 0], acc);
            acc = fmaf(hv.y, w[q * 4 + 1], acc);
            acc = fmaf(hv.z, w[q * 4 + 2], acc);
            acc = fmaf(hv.w, w[q * 4 + 3], acc);
        }
        acc += __shfl_xor(acc, 32, 64);        // merge k-halves
        if (half == 0)
            h2s[(((unsigned)n) << 5) + cls] = f2e5(acc * dn);
    }
}

// ---------------- layer 2 gather + bias + log_softmax (16 gathers in flight) ----------------

__global__ __launch_bounds__(256) void k_out(const int* __restrict__ cnt,
                                             const int* __restrict__ slots,
                                             const float* __restrict__ dinv,
                                             const unsigned char* __restrict__ h2s,
                                             const float* __restrict__ b2,
                                             float* __restrict__ out) {
    int wid = blockIdx.x * 4 + (threadIdx.x >> 6);
    int n = __builtin_amdgcn_readfirstlane(wid);
    if (n >= N_NODES) return;
    int lane = threadIdx.x & 63;
    int cls = lane & 31;
    int half = lane >> 5;
    float dn = dinv[n];
    int deg = min(cnt[n], CAP);
    int degp = (deg + 15) & ~15;
    size_t base = (size_t)n * CAP;
    float a0 = half ? 0.f : e52f(h2s[(((unsigned)n) << 5) + cls]);   // self in low half
    float a1 = 0.f, a2 = 0.f, a3 = 0.f;
    for (int j = 0; j < degp; j += 16) {
        intx4 s0 = *reinterpret_cast<const intx4*>(&slots[base + j + half * 8]);
        intx4 s1 = *reinterpret_cast<const intx4*>(&slots[base + j + half * 8 + 4]);
        a0 += e52f(h2s[(((unsigned)s0.x) << 5) + cls]);
        a1 += e52f(h2s[(((unsigned)s0.y) << 5) + cls]);
        a2 += e52f(h2s[(((unsigned)s0.z) << 5) + cls]);
        a3 += e52f(h2s[(((unsigned)s0.w) << 5) + cls]);
        a0 += e52f(h2s[(((unsigned)s1.x) << 5) + cls]);
        a1 += e52f(h2s[(((unsigned)s1.y) << 5) + cls]);
        a2 += e52f(h2s[(((unsigned)s1.z) << 5) + cls]);
        a3 += e52f(h2s[(((unsigned)s1.w) << 5) + cls]);
    }
    float acc = (a0 + a1) + (a2 + a3);
    acc += __shfl_xor(acc, 32, 64);          // merge halves
    float z = fmaf(acc, dn, b2[cls]);
    float mx = z;
    #pragma unroll
    for (int d = 16; d > 0; d >>= 1) mx = fmaxf(mx, __shfl_xor(mx, d, 32));
    float ex = expf(z - mx);
    float sm = ex;
    #pragma unroll
    for (int d = 16; d > 0; d >>= 1) sm += __shfl_xor(sm, d, 32);
    if (half == 0)
        out[(size_t)n * NCLS + cls] = z - mx - logf(sm);
}

// ---------------- launch ----------------

extern "C" void kernel_launch(void* const* d_in, const int* in_sizes, int n_in,
                              void* d_out, int out_size, void* d_ws, size_t ws_size,
                              hipStream_t stream) {
    const float* x  = (const float*)d_in[0];
    const int*   ei = (const int*)d_in[1];
    const float* W1 = (const float*)d_in[2];
    const float* b1 = (const float*)d_in[3];
    const float* W2 = (const float*)d_in[4];
    const float* b2 = (const float*)d_in[5];
    float* out = (float*)d_out;
    char* ws = (char*)d_ws;

    const int* src = ei;
    const int* dst = ei + N_EDGES;

    // workspace layout (bytes, 16B-aligned); h1 eliminated
    int*   gtail = (int*)ws;                                       // 16384
    int*   cnt   = (int*)(ws + 16384);                             // 400000
    float* dinv  = (float*)(ws + 416384);                          // 400000
    unsigned short* W1T = (unsigned short*)(ws + 816384);          // 65536
    int*   slots = (int*)(ws + 881920);                            // 32,000,000 (+64 pad)
    unsigned char* h1s = (unsigned char*)(ws + 45682048ull);       // 6,400,128
    char*  recs_base   = ws + 52082176ull;                         // NB*BCAPC*4 = 13,309,184
    int*   recs  = (int*)recs_base;
    unsigned char* h2s  = (unsigned char*)(ws + 65391360ull);      // 3,200,032

    k_prep<<<129, 256, 0, stream>>>(W1, W1T, h1s, h2s, gtail, cnt);
    k_part<<<PART_BLOCKS, 512, 0, stream>>>(src, dst, gtail, recs);
    k_phase2<<<NB * 4, 512, 0, stream>>>(gtail, recs, slots, cnt);
    k_phase2b<<<(N_NODES + 511) / 512, 512, 0, stream>>>(slots, cnt, dinv);
    k_gemm1<<<GEMM1_BLOCKS, 256, 0, stream>>>(x, W1T, dinv, h1s);
    k_gather1<<<1536, 256, 0, stream>>>(cnt, slots, dinv, h1s, b1, W2, h2s);
    k_out<<<(N_NODES + 3) / 4, 256, 0, stream>>>(cnt, slots, dinv, h2s, b2, out);
}

// Round 13
// 194.117 us; speedup vs baseline: 1.3693x; 1.3693x over previous
//
#include <hip/hip_runtime.h>
#include <hip/hip_fp16.h>
#include <math.h>

constexpr int N_NODES = 100000;
constexpr int N_EDGES = 3200000;
constexpr int IN_F = 512;
constexpr int HID = 64;
constexpr int NCLS = 32;
constexpr int CAP = 80;            // per-node slot capacity (multiple of 16); P(indeg>=80) ~ 1e-13
constexpr int SHIFT = 9;           // 512 nodes per coarse bucket
constexpr int NB = 196;            // ceil(100000/512)
constexpr int BCAPC = 16976;       // per-bucket capacity: mean 16327 + ~5 sigma
constexpr int CHUNK = 8192;        // edges per partition block (big: fewer gtail atomics/line)
constexpr int SENT = N_NODES;      // sentinel node id (zeroed rows)

constexpr int GEMM1_BLOCKS = (N_NODES + 63) / 64;            // 1563
constexpr int PART_BLOCKS  = (N_EDGES + CHUNK - 1) / CHUNK;  // 391

typedef short short8 __attribute__((ext_vector_type(8)));    // 8 bf16 in 4 VGPRs
typedef float f32x4 __attribute__((ext_vector_type(4)));
typedef int intx4 __attribute__((ext_vector_type(4)));

// ---------- bf16 helpers (bit-level, RNE) ----------
__device__ __forceinline__ unsigned short f2bf(float f) {
    union { float f; unsigned int u; } v; v.f = f;
    unsigned int r = (v.u + 0x7fffu + ((v.u >> 16) & 1u)) >> 16;
    return (unsigned short)r;
}
__device__ __forceinline__ float bf2f(unsigned short h) {
    union { unsigned int u; float f; } v; v.u = ((unsigned int)h) << 16;
    return v.f;
}
// ---------- fp8 e5m2 helpers (top byte of f16, RNE) ----------
__device__ __forceinline__ unsigned char f2e5(float f) {
    unsigned short u = __half_as_ushort(__float2half(f));
    return (unsigned char)((u + 0x7Fu + ((u >> 8) & 1u)) >> 8);
}
__device__ __forceinline__ float e52f(unsigned char b) {
    return __half2float(__ushort_as_half((unsigned short)((unsigned short)b << 8)));
}
// ---------- async 16B global->LDS ----------
__device__ __forceinline__ void gload16(const void* g, void* l) {
    __builtin_amdgcn_global_load_lds((const __attribute__((address_space(1))) unsigned int*)g,
                                     (__attribute__((address_space(3))) unsigned int*)l,
                                     16, 0, 0);
}

// ---------------- prep: W1T bf16 [64][512]; zero sentinel rows + gtail ----------------
__global__ __launch_bounds__(256) void k_prep(const float* __restrict__ W1,
                                              unsigned short* __restrict__ W1T,
                                              unsigned char* __restrict__ h1s,
                                              unsigned char* __restrict__ h2s,
                                              int* __restrict__ gtail) {
    if (blockIdx.x == 128) {
        int t = threadIdx.x;
        if (t < HID)  h1s[(size_t)SENT * HID + t] = 0;
        if (t < NCLS) h2s[(size_t)SENT * NCLS + t] = 0;
        for (int i = t; i < NB * 16; i += 256) gtail[i] = 0;   // replaces hipMemsetAsync
        return;
    }
    int t = blockIdx.x * 256 + threadIdx.x;     // 0..32767
    int k = t >> 6, c = t & 63;
    W1T[(size_t)c * IN_F + k] = f2bf(W1[(size_t)k * HID + c]);
}

// ---------------- partition: 8192 edges/block, 512 thr, 1-pass rank + shfl scan ----------------

__global__ __launch_bounds__(512) void k_part(const int* __restrict__ src,
                                              const int* __restrict__ dst,
                                              int* __restrict__ gtail,   // [NB*16] line-padded
                                              int* __restrict__ recs) {  // [NB*BCAPC] packed ln<<17|src
    __shared__ alignas(16) char smem[47168];
    int* buf            = (int*)smem;                    // 32768 B
    unsigned char* bbuf = (unsigned char*)(smem + 32768);// 8192 B
    int* loc   = (int*)(smem + 40960);                   // 513 ints
    int* lh    = (int*)(smem + 43012);                   // 512 ints
    int* lbase = (int*)(smem + 45060);                   // 512 ints
    int* wsum  = (int*)(smem + 47108);                   // 8 ints
    const int tid = threadIdx.x;
    const int lane = tid & 63;
    const int wv = tid >> 6;                             // 0..7
    const int c0 = blockIdx.x * CHUNK;
    const int cnum = min(CHUNK, N_EDGES - c0);
    lh[tid] = 0;
    __syncthreads();
    int dd[16], ss[16], rk[16];
    #pragma unroll
    for (int k = 0; k < 16; ++k) {
        int i = k * 512 + tid;
        if (i < cnum) {
            dd[k] = dst[c0 + i];
            ss[k] = src[c0 + i];
            rk[k] = atomicAdd(&lh[dd[k] >> SHIFT], 1);   // count AND local rank (LDS)
        }
    }
    __syncthreads();
    int orig = lh[tid];
    // barrier-free scan: wave shfl inclusive scan + wave-sum combine
    int v = orig;
    #pragma unroll
    for (int off = 1; off < 64; off <<= 1) {
        int t = __shfl_up(v, off, 64);
        if (lane >= off) v += t;
    }
    if (lane == 63) wsum[wv] = v;
    __syncthreads();
    int pre = 0;
    #pragma unroll
    for (int k = 0; k < 8; ++k) if (k < wv) pre += wsum[k];
    int incl = v + pre;
    loc[tid] = incl - orig;                              // exclusive prefix
    if (tid < NB && orig > 0) lbase[tid] = atomicAdd(&gtail[tid * 16], orig);
    __syncthreads();
    #pragma unroll
    for (int k = 0; k < 16; ++k) {
        int i = k * 512 + tid;
        if (i < cnum) {
            int b = dd[k] >> SHIFT;
            int pos = loc[b] + rk[k];
            buf[pos] = ((dd[k] & 511) << 17) | ss[k];
            bbuf[pos] = (unsigned char)b;
        }
    }
    __syncthreads();
    for (int i = tid; i < cnum; i += 512) {              // contiguous run write-out
        int b = bbuf[i];
        int idx = lbase[b] + (i - loc[b]);
        if (idx < BCAPC) recs[(size_t)b * BCAPC + idx] = buf[i];
    }
}

// ---------------- phase 2a (1024 thr): slot placement + sentinel pad (to 16) + cnt/dinv ----

__global__ __launch_bounds__(1024) void k_phase2(const int* __restrict__ gtail,
                                                 const int* __restrict__ recs,
                                                 int* __restrict__ slots,
                                                 int* __restrict__ cnt,
                                                 float* __restrict__ dinv) {
    __shared__ int scnt[512];
    const int b = blockIdx.x;
    const int tid = threadIdx.x;
    if (tid < 512) scnt[tid] = 0;
    __syncthreads();
    int nrec = min(gtail[b * 16], BCAPC);
    const int* rb = recs + (size_t)b * BCAPC;
    for (int i = tid; i < nrec; i += 1024) {
        int r = rb[i];
        int ln = r >> 17;
        int s  = r & 0x1FFFF;
        int p = atomicAdd(&scnt[ln], 1);
        int node = (b << SHIFT) + ln;
        if (p < CAP) slots[(size_t)node * CAP + p] = s;
    }
    __syncthreads();
    if (tid < 512) {
        int node = (b << SHIFT) + tid;
        if (node < N_NODES) {
            int c = scnt[tid];
            cnt[node] = c;
            dinv[node] = rsqrtf(1.0f + (float)c);
            int c2 = min(c, CAP);
            int degp = (c2 + 15) & ~15;                     // pad to 16 for unroll-16 gathers
            for (int p = c2; p < degp; ++p) slots[(size_t)node * CAP + p] = SENT;
        }
    }
}

// ---------------- GEMM1: h1s = fp8(dinv * (x @ W1)), 64x64 tile, 4-deep async pipeline ----

__global__ __launch_bounds__(256) void k_gemm1(const float* __restrict__ x,
                                               const unsigned short* __restrict__ W1T,
                                               const float* __restrict__ dinv,
                                               unsigned char* __restrict__ h1s) {
    __shared__ alignas(16) char smem[49152];
    float* Xf = (float*)smem;                            // [4][64][32] f32, 32768 B
    unsigned short* Wf = (unsigned short*)(smem + 32768);// [4][64][32] bf16, 16384 B
    const int tid = threadIdx.x;
    const int lane = tid & 63;
    const int row0 = blockIdx.x * 64;
    const int w = tid >> 6;
    const int r0l = (w >> 1) * 32;
    const int c0l = (w & 1) * 32;
    const int lrow = lane & 15;
    const int lkb = (lane >> 4) << 3;                    // k offset 0,8,16,24
    f32x4 acc00 = {0.f, 0.f, 0.f, 0.f}, acc01 = acc00, acc10 = acc00, acc11 = acc00;

    const int rowA0 = tid >> 3;            // issue0: rows 0..31
    const int rowA1 = 32 + (tid >> 3);     // issue1: rows 32..63
    const int gA = tid & 7;                // 16B granule within 128B row
    const float* srcX0 = x + (size_t)min(row0 + rowA0, N_NODES - 1) * IN_F + ((gA ^ (rowA0 & 7)) << 2);
    const float* srcX1 = x + (size_t)min(row0 + rowA1, N_NODES - 1) * IN_F + ((gA ^ (rowA1 & 7)) << 2);
    const int rowW = tid >> 2;
    const int gW = tid & 3;                // 16B granule within 64B row
    const unsigned short* srcW = W1T + (size_t)rowW * IN_F + ((gW ^ (rowW & 3)) << 3);
    char* ldsX0 = smem + (w << 10);
    char* ldsX1 = smem + 4096 + (w << 10);
    char* ldsW  = smem + 32768 + (w << 10);

    #pragma unroll
    for (int s = 0; s < 3; ++s) {
        gload16(srcX0 + s * 32, ldsX0 + s * 8192);
        gload16(srcX1 + s * 32, ldsX1 + s * 8192);
        gload16(srcW  + s * 32, ldsW  + s * 4096);
    }

    const int RA = r0l + lrow, RA2 = RA + 16;
    const int RB = c0l + lrow, RB2 = RB + 16;
    const int qx = lkb >> 2;               // X granule pair base (0,2,4,6)
    const int qw = lkb >> 3;               // W granule (0..3)
    const int sxA  = ((qx ^ (RA & 7)) << 2),  sxA_ = (((qx + 1) ^ (RA & 7)) << 2);
    const int sxB  = ((qx ^ (RA2 & 7)) << 2), sxB_ = (((qx + 1) ^ (RA2 & 7)) << 2);
    const int swB  = ((qw ^ (RB & 3)) << 3);
    const int swB2 = ((qw ^ (RB2 & 3)) << 3);

#define GEMM_COMPUTE(S)                                                          \
    {                                                                            \
        const int b_ = (S) & 3;                                                  \
        const float* xrA = Xf + b_ * 2048 + RA * 32;                             \
        const float* xrB = Xf + b_ * 2048 + RA2 * 32;                            \
        f32x4 va0 = *(const f32x4*)(xrA + sxA);                                  \
        f32x4 va1 = *(const f32x4*)(xrA + sxA_);                                 \
        f32x4 vb0 = *(const f32x4*)(xrB + sxB);                                  \
        f32x4 vb1 = *(const f32x4*)(xrB + sxB_);                                 \
        const unsigned short* wr = Wf + b_ * 2048;                               \
        short8 b0 = *(const short8*)(wr + RB * 32 + swB);                        \
        short8 b1 = *(const short8*)(wr + RB2 * 32 + swB2);                      \
        short8 a0, a1;                                                           \
        a0[0] = (short)f2bf(va0[0]); a0[1] = (short)f2bf(va0[1]);                \
        a0[2] = (short)f2bf(va0[2]); a0[3] = (short)f2bf(va0[3]);                \
        a0[4] = (short)f2bf(va1[0]); a0[5] = (short)f2bf(va1[1]);                \
        a0[6] = (short)f2bf(va1[2]); a0[7] = (short)f2bf(va1[3]);                \
        a1[0] = (short)f2bf(vb0[0]); a1[1] = (short)f2bf(vb0[1]);                \
        a1[2] = (short)f2bf(vb0[2]); a1[3] = (short)f2bf(vb0[3]);                \
        a1[4] = (short)f2bf(vb1[0]); a1[5] = (short)f2bf(vb1[1]);                \
        a1[6] = (short)f2bf(vb1[2]); a1[7] = (short)f2bf(vb1[3]);                \
        acc00 = __builtin_amdgcn_mfma_f32_16x16x32_bf16(a0, b0, acc00, 0, 0, 0); \
        acc01 = __builtin_amdgcn_mfma_f32_16x16x32_bf16(a0, b1, acc01, 0, 0, 0); \
        acc10 = __builtin_amdgcn_mfma_f32_16x16x32_bf16(a1, b0, acc10, 0, 0, 0); \
        acc11 = __builtin_amdgcn_mfma_f32_16x16x32_bf16(a1, b1, acc11, 0, 0, 0); \
    }

    for (int s = 0; s < 14; ++s) {
        asm volatile("s_waitcnt vmcnt(6)" ::: "memory");   // step-s loads landed (mine)
        __builtin_amdgcn_s_barrier();                      // ...and everyone's
        __builtin_amdgcn_sched_barrier(0);
        if (s < 13) {
            gload16(srcX0 + (s + 3) * 32, ldsX0 + ((s + 3) & 3) * 8192);
            gload16(srcX1 + (s + 3) * 32, ldsX1 + ((s + 3) & 3) * 8192);
            gload16(srcW  + (s + 3) * 32, ldsW  + ((s + 3) & 3) * 4096);
        }
        GEMM_COMPUTE(s);
    }
    asm volatile("s_waitcnt vmcnt(3)" ::: "memory");
    __builtin_amdgcn_s_barrier();
    __builtin_amdgcn_sched_barrier(0);
    GEMM_COMPUTE(14);
    asm volatile("s_waitcnt vmcnt(0)" ::: "memory");
    __builtin_amdgcn_s_barrier();
    __builtin_amdgcn_sched_barrier(0);
    GEMM_COMPUTE(15);
#undef GEMM_COMPUTE

    const int vr0 = row0 + r0l + ((lane >> 4) << 2);
    const int gc0 = c0l + (lane & 15);
    #pragma unroll
    for (int v = 0; v < 4; ++v) {
        int gr = vr0 + v;
        if (gr < N_NODES) {
            float dv = dinv[gr];
            h1s[(size_t)gr * HID + gc0]      = f2e5(acc00[v] * dv);
            h1s[(size_t)gr * HID + gc0 + 16] = f2e5(acc01[v] * dv);
        }
        int gr2 = gr + 16;
        if (gr2 < N_NODES) {
            float dv2 = dinv[gr2];
            h1s[(size_t)gr2 * HID + gc0]      = f2e5(acc10[v] * dv2);
            h1s[(size_t)gr2 * HID + gc0 + 16] = f2e5(acc11[v] * dv2);
        }
    }
}

// ---------------- fused gather1 + GEMM2: h2s = fp8(dinv * (relu(agg) @ W2)) ----------------
// Wave-per-node, grid-stride; 16 gathers in flight per round. Slot loads are
// TEMPORAL (retained in L2) so k_out's second pass over slots hits cache.

__global__ __launch_bounds__(256) void k_gather1(const int* __restrict__ cnt,
                                                 const int* __restrict__ slots,
                                                 const float* __restrict__ dinv,
                                                 const unsigned char* __restrict__ h1s,
                                                 const float* __restrict__ b1,
                                                 const float* __restrict__ W2,
                                                 unsigned char* __restrict__ h2s) {
    __shared__ alignas(16) float hsh[4][64];
    const int lane = threadIdx.x & 63;
    const int wv = threadIdx.x >> 6;
    const int cls = lane & 31;
    const int half = lane >> 5;
    float w[32];
    #pragma unroll
    for (int j = 0; j < 32; ++j)
        w[j] = W2[(size_t)(half * 32 + j) * NCLS + cls];
    const float bb = b1[lane];
    const int nw = gridDim.x * 4;
    for (int n0 = blockIdx.x * 4 + wv; n0 < N_NODES; n0 += nw) {
        const int n = __builtin_amdgcn_readfirstlane(n0);
        float dn = dinv[n];
        int deg = min(cnt[n], CAP);
        int degp = (deg + 15) & ~15;
        size_t base = (size_t)n * CAP;
        float a0 = e52f(h1s[(((unsigned)n) << 6) + lane]);   // self (already dinv[n]-scaled)
        float a1 = 0.f, a2 = 0.f, a3 = 0.f, a4 = 0.f, a5 = 0.f, a6 = 0.f, a7 = 0.f;
        for (int j = 0; j < degp; j += 16) {
            intx4 sa = *reinterpret_cast<const intx4*>(&slots[base + j]);
            intx4 sb = *reinterpret_cast<const intx4*>(&slots[base + j + 4]);
            intx4 sc = *reinterpret_cast<const intx4*>(&slots[base + j + 8]);
            intx4 sd = *reinterpret_cast<const intx4*>(&slots[base + j + 12]);
            a0 += e52f(h1s[(((unsigned)sa.x) << 6) + lane]);
            a1 += e52f(h1s[(((unsigned)sa.y) << 6) + lane]);
            a2 += e52f(h1s[(((unsigned)sa.z) << 6) + lane]);
            a3 += e52f(h1s[(((unsigned)sa.w) << 6) + lane]);
            a4 += e52f(h1s[(((unsigned)sb.x) << 6) + lane]);
            a5 += e52f(h1s[(((unsigned)sb.y) << 6) + lane]);
            a6 += e52f(h1s[(((unsigned)sb.z) << 6) + lane]);
            a7 += e52f(h1s[(((unsigned)sb.w) << 6) + lane]);
            a0 += e52f(h1s[(((unsigned)sc.x) << 6) + lane]);
            a1 += e52f(h1s[(((unsigned)sc.y) << 6) + lane]);
            a2 += e52f(h1s[(((unsigned)sc.z) << 6) + lane]);
            a3 += e52f(h1s[(((unsigned)sc.w) << 6) + lane]);
            a4 += e52f(h1s[(((unsigned)sd.x) << 6) + lane]);
            a5 += e52f(h1s[(((unsigned)sd.y) << 6) + lane]);
            a6 += e52f(h1s[(((unsigned)sd.z) << 6) + lane]);
            a7 += e52f(h1s[(((unsigned)sd.w) << 6) + lane]);
        }
        float v = fmaf(((a0 + a1) + (a2 + a3)) + ((a4 + a5) + (a6 + a7)), dn, bb);
        v = fmaxf(v, 0.f);                     // h1r value for feature `lane`, fp32
        hsh[wv][lane] = v;
        // in-wave 64x32 matvec: lane (cls,half) accumulates its half of k
        float acc = 0.f;
        #pragma unroll
        for (int q = 0; q < 8; ++q) {
            f32x4 hv = *reinterpret_cast<const f32x4*>(&hsh[wv][half * 32 + q * 4]);
            acc = fmaf(hv.x, w[q * 4 + 0], acc);
            acc = fmaf(hv.y, w[q * 4 + 1], acc);
            acc = fmaf(hv.z, w[q * 4 + 2], acc);
            acc = fmaf(hv.w, w[q * 4 + 3], acc);
        }
        acc += __shfl_xor(acc, 32, 64);        // merge k-halves
        if (half == 0)
            h2s[(((unsigned)n) << 5) + cls] = f2e5(acc * dn);
    }
}

// ---------------- layer 2 gather + bias + log_softmax (16 gathers in flight) ----------------

__global__ __launch_bounds__(256) void k_out(const int* __restrict__ cnt,
                                             const int* __restrict__ slots,
                                             const float* __restrict__ dinv,
                                             const unsigned char* __restrict__ h2s,
                                             const float* __restrict__ b2,
                                             float* __restrict__ out) {
    int wid = blockIdx.x * 4 + (threadIdx.x >> 6);
    int n = __builtin_amdgcn_readfirstlane(wid);
    if (n >= N_NODES) return;
    int lane = threadIdx.x & 63;
    int cls = lane & 31;
    int half = lane >> 5;
    float dn = dinv[n];
    int deg = min(cnt[n], CAP);
    int degp = (deg + 15) & ~15;
    size_t base = (size_t)n * CAP;
    float a0 = half ? 0.f : e52f(h2s[(((unsigned)n) << 5) + cls]);   // self in low half
    float a1 = 0.f, a2 = 0.f, a3 = 0.f;
    for (int j = 0; j < degp; j += 16) {
        intx4 s0 = *reinterpret_cast<const intx4*>(&slots[base + j + half * 8]);
        intx4 s1 = *reinterpret_cast<const intx4*>(&slots[base + j + half * 8 + 4]);
        a0 += e52f(h2s[(((unsigned)s0.x) << 5) + cls]);
        a1 += e52f(h2s[(((unsigned)s0.y) << 5) + cls]);
        a2 += e52f(h2s[(((unsigned)s0.z) << 5) + cls]);
        a3 += e52f(h2s[(((unsigned)s0.w) << 5) + cls]);
        a0 += e52f(h2s[(((unsigned)s1.x) << 5) + cls]);
        a1 += e52f(h2s[(((unsigned)s1.y) << 5) + cls]);
        a2 += e52f(h2s[(((unsigned)s1.z) << 5) + cls]);
        a3 += e52f(h2s[(((unsigned)s1.w) << 5) + cls]);
    }
    float acc = (a0 + a1) + (a2 + a3);
    acc += __shfl_xor(acc, 32, 64);          // merge halves
    float z = fmaf(acc, dn, b2[cls]);
    float mx = z;
    #pragma unroll
    for (int d = 16; d > 0; d >>= 1) mx = fmaxf(mx, __shfl_xor(mx, d, 32));
    float ex = expf(z - mx);
    float sm = ex;
    #pragma unroll
    for (int d = 16; d > 0; d >>= 1) sm += __shfl_xor(sm, d, 32);
    if (half == 0)
        out[(size_t)n * NCLS + cls] = z - mx - logf(sm);
}

// ---------------- launch ----------------

extern "C" void kernel_launch(void* const* d_in, const int* in_sizes, int n_in,
                              void* d_out, int out_size, void* d_ws, size_t ws_size,
                              hipStream_t stream) {
    const float* x  = (const float*)d_in[0];
    const int*   ei = (const int*)d_in[1];
    const float* W1 = (const float*)d_in[2];
    const float* b1 = (const float*)d_in[3];
    const float* W2 = (const float*)d_in[4];
    const float* b2 = (const float*)d_in[5];
    float* out = (float*)d_out;
    char* ws = (char*)d_ws;

    const int* src = ei;
    const int* dst = ei + N_EDGES;

    // workspace layout (bytes, 16B-aligned); h1 eliminated
    int*   gtail = (int*)ws;                                       // 16384
    int*   cnt   = (int*)(ws + 16384);                             // 400000
    float* dinv  = (float*)(ws + 416384);                          // 400000
    unsigned short* W1T = (unsigned short*)(ws + 816384);          // 65536
    int*   slots = (int*)(ws + 881920);                            // 32,000,000 (+64 pad)
    unsigned char* h1s = (unsigned char*)(ws + 45682048ull);       // 6,400,128
    char*  recs_base   = ws + 52082176ull;                         // NB*BCAPC*4 = 13,309,184
    int*   recs  = (int*)recs_base;
    unsigned char* h2s  = (unsigned char*)(ws + 65391360ull);      // 3,200,032

    k_prep<<<129, 256, 0, stream>>>(W1, W1T, h1s, h2s, gtail);
    k_part<<<PART_BLOCKS, 512, 0, stream>>>(src, dst, gtail, recs);
    k_phase2<<<NB, 1024, 0, stream>>>(gtail, recs, slots, cnt, dinv);
    k_gemm1<<<GEMM1_BLOCKS, 256, 0, stream>>>(x, W1T, dinv, h1s);
    k_gather1<<<1536, 256, 0, stream>>>(cnt, slots, dinv, h1s, b1, W2, h2s);
    k_out<<<(N_NODES + 3) / 4, 256, 0, stream>>>(cnt, slots, dinv, h2s, b2, out);
}